// Round 1
// baseline (429.312 us; speedup 1.0000x reference)
//
#include <hip/hip_runtime.h>
#include <hip/hip_bf16.h>

// out[n, d] = in[n, d] * W[d]   (N=16384, D=4096, fp32)
// Memory-bound: 512 MiB total traffic -> roofline ~85 us at 6.3 TB/s.
// float4 vectorization; W indexed per float4-group with & 1023 (D/4 = 1024).

__global__ void Diag_14285061227129_kernel(const float4* __restrict__ in,
                                           const float4* __restrict__ W4,
                                           float4* __restrict__ out,
                                           long long n4) {
    long long i = (long long)blockIdx.x * blockDim.x + threadIdx.x;
    long long stride = (long long)gridDim.x * blockDim.x;
    for (; i < n4; i += stride) {
        float4 v = in[i];
        float4 w = W4[i & 1023];   // (i % (D/4)); D/4 = 1024
        v.x *= w.x;
        v.y *= w.y;
        v.z *= w.z;
        v.w *= w.w;
        out[i] = v;
    }
}

extern "C" void kernel_launch(void* const* d_in, const int* in_sizes, int n_in,
                              void* d_out, int out_size, void* d_ws, size_t ws_size,
                              hipStream_t stream) {
    const float4* in = (const float4*)d_in[0];
    const float4* W4 = (const float4*)d_in[1];
    float4* out = (float4*)d_out;

    const long long n4 = (long long)out_size / 4;  // 67,108,864 / 4 = 16,777,216

    // 256 CUs; oversubscribe with grid-stride. 8192 blocks x 256 threads
    // = 2,097,152 threads -> 8 float4 iterations each.
    const int block = 256;
    const int grid = 8192;
    Diag_14285061227129_kernel<<<grid, block, 0, stream>>>(in, W4, out, n4);
}